// Round 3
// baseline (1740.093 us; speedup 1.0000x reference)
//
#include <hip/hip_runtime.h>
#include <hip/hip_bf16.h>
#include <math.h>

#define SD 32
#define NSPA 32768          // 32^3
#define NC 192
#define NB 2
#define NHD 8
#define HDIM 24

typedef __bf16 bf16x8 __attribute__((ext_vector_type(8)));
typedef float f32x4 __attribute__((ext_vector_type(4)));

__device__ __forceinline__ float gelu_f(float x) {
    return 0.5f * x * (1.0f + erff(x * 0.70710678118654752f));
}

__device__ __forceinline__ ushort bfr(float x) {   // fp32 -> bf16 bits, RNE
    unsigned u = __float_as_uint(x);
    unsigned r = (u + 0x7fffu + ((u >> 16) & 1u)) >> 16;
    return (ushort)r;
}

// ---------------------------------------------------------------------------
// Rotation matrices R[axis][h][l][3][3] (Rodrigues, numeric K@K like ref)
// ---------------------------------------------------------------------------
__global__ void rot_kernel(const float* __restrict__ Ad, const float* __restrict__ Ah,
                           const float* __restrict__ Aw, float* __restrict__ R)
{
    int idx = blockIdx.x * 256 + threadIdx.x;   // 0..767
    if (idx >= 768) return;
    int l = idx & 31;
    int h = (idx >> 5) & 7;
    int axis = idx >> 8;
    const float* A = (axis == 0) ? Ad : ((axis == 1) ? Ah : Aw);
    int comp = (axis == 0) ? 2 : ((axis == 1) ? 1 : 0);
    float p = -1.0f + 2.0f * (float)l / 31.0f;
    float w0 = p * A[h * 9 + 0 * 3 + comp];
    float w1 = p * A[h * 9 + 1 * 3 + comp];
    float w2 = p * A[h * 9 + 2 * 3 + comp];
    float th = sqrtf(w0 * w0 + w1 * w1 + w2 * w2);
    th = fmaxf(th, 1e-8f);
    float ux = w0 / th, uy = w1 / th, uz = w2 / th;
    float K[3][3] = {{0.f, -uz, uy}, {uz, 0.f, -ux}, {-uy, ux, 0.f}};
    float K2[3][3];
    #pragma unroll
    for (int i = 0; i < 3; ++i)
        #pragma unroll
        for (int j = 0; j < 3; ++j) {
            float s = 0.f;
            #pragma unroll
            for (int k = 0; k < 3; ++k) s += K[i][k] * K[k][j];
            K2[i][j] = s;
        }
    float s = sinf(th), c = cosf(th);
    float* out = R + (size_t)idx * 9;
    #pragma unroll
    for (int i = 0; i < 3; ++i)
        #pragma unroll
        for (int j = 0; j < 3; ++j)
            out[i * 3 + j] = ((i == j) ? 1.0f : 0.0f) + s * K[i][j] + (1.0f - c) * K2[i][j];
}

// ---------------------------------------------------------------------------
// Input repack: pos_emb fp32 -> bf16 hi/lo, [b][cc48][pos][8]
// ---------------------------------------------------------------------------
__global__ __launch_bounds__(256) void xcvt_kernel(const float* __restrict__ in,
                                                   ushort* __restrict__ xb)
{
    __shared__ float lds[192][66];
    int t = threadIdx.x;
    int pos0 = blockIdx.x * 64;
    int b = blockIdx.y;
    #pragma unroll 4
    for (int i = 0; i < 48; ++i) {
        int idx = t + 256 * i;
        int ci = idx >> 6, col = idx & 63;
        lds[ci][col] = in[((size_t)(b * NC + ci) << 15) + pos0 + col];
    }
    __syncthreads();
    int p = t & 63;
    int ccb = t >> 6;
    #pragma unroll
    for (int i = 0; i < 12; ++i) {
        int cc = i * 4 + ccb;
        unsigned ov[4];
        #pragma unroll
        for (int k = 0; k < 4; ++k) {
            float x = lds[cc * 4 + k][p];
            ushort hi = bfr(x);
            float hif = __uint_as_float((unsigned)hi << 16);
            ushort lo = bfr(x - hif);
            ov[k] = (unsigned)hi | ((unsigned)lo << 16);
        }
        *(uint4*)(xb + ((((size_t)(b * 48 + cc)) << 15) + pos0 + p) * 8) = *(uint4*)ov;
    }
}

// ---------------------------------------------------------------------------
// Weight repack: lp1_w fp32 [co][ci][27] -> wb bf16 [cc48][tap28][co192][8]
// ---------------------------------------------------------------------------
__global__ __launch_bounds__(256) void wcvt_kernel(const float* __restrict__ wgt,
                                                   ushort* __restrict__ wb)
{
    int slot = blockIdx.x * 256 + threadIdx.x;
    if (slot >= 48 * 28 * 192) return;
    int cc = slot / (28 * 192);
    int r = slot % (28 * 192);
    int tap = r / 192, co = r % 192;
    unsigned ov[4];
    #pragma unroll
    for (int k = 0; k < 4; ++k) {
        int ci = cc * 4 + k;
        float w = (tap < 27) ? wgt[((size_t)co * NC + ci) * 27 + tap] : 0.f;
        ushort wv = bfr(w);
        ov[k] = (unsigned)wv | ((unsigned)wv << 16);
    }
    *(uint4*)(wb + (size_t)slot * 8) = *(uint4*)ov;
}

// ---------------------------------------------------------------------------
// Circular 3x3x3 conv as implicit-GEMM MFMA (bf16, hi/lo split input).
// ---------------------------------------------------------------------------
#define LIN_BYTES (4 * 10 * 32 * 16)   // 20480
#define LW_BYTES  (28 * 65 * 16)       // 29120

__global__ __launch_bounds__(256, 2) void conv3_mfma(
        const ushort* __restrict__ xb, const ushort* __restrict__ wb,
        const float* __restrict__ bias, float* __restrict__ out)
{
    __shared__ __align__(16) char smem[LIN_BYTES + LW_BYTES];
    char* lin = smem;
    char* lw  = smem + LIN_BYTES;
    int tid = threadIdx.x;
    int co0 = blockIdx.x * 64;
    int sp  = blockIdx.y;               // 0..63
    int b   = blockIdx.z;
    int d0 = (sp >> 2) * 2;
    int h0 = (sp & 3) * 8;
    int lane = tid & 63, wv = tid >> 6;
    int g = lane >> 4, c = lane & 15;

    int aoff[7], brow[7], bdx[7];
    #pragma unroll
    for (int s = 0; s < 7; ++s) {
        int tap = 4 * s + g;
        aoff[s] = (tap * 65 + c) * 16;
        int tc = tap > 26 ? 26 : tap;
        int dz = tc / 9, r = tc % 9, dy = r / 3, dx = r % 3;
        brow[s] = (dz * 10 + dy) * 512;
        bdx[s] = dx - 1;
    }
    int nb[8], wn[8];
    #pragma unroll
    for (int n = 0; n < 8; ++n) {
        int posl = wv * 128 + n * 16 + c;
        int dof = posl >> 8, rem = posl & 255;
        nb[n] = dof * 5120 + (rem >> 5) * 512;
        wn[n] = rem & 31;
    }

    int xoff[5];
    #pragma unroll
    for (int k = 0; k < 5; ++k) {
        int i = tid + 256 * k;
        int dz = i / 320, r2 = i % 320, hh = r2 >> 5, ww = r2 & 31;
        int dd = (d0 + dz + 31) & 31, hg = (h0 + hh + 31) & 31;
        xoff[k] = (dd << 10) + (hg << 5) + ww;
    }
    int wco = tid & 63;
    int wtap = tid >> 6;

    f32x4 acc[4][8];
    #pragma unroll
    for (int m = 0; m < 4; ++m)
        #pragma unroll
        for (int n = 0; n < 8; ++n)
            acc[m][n] = (f32x4){0.f, 0.f, 0.f, 0.f};

    const size_t xbb = ((size_t)b * 48) << 15;

    for (int cc = 0; cc < 48; ++cc) {
        const ushort* xsrc = xb + ((xbb + ((size_t)cc << 15)) << 3);
        uint4 xi[5];
        #pragma unroll
        for (int k = 0; k < 5; ++k)
            xi[k] = *(const uint4*)(xsrc + ((size_t)xoff[k] << 3));
        const ushort* wsrc = wb + (((size_t)cc * 28 * 192) << 3);
        uint4 wi[7];
        #pragma unroll
        for (int k = 0; k < 7; ++k) {
            int tap = wtap + 4 * k;
            wi[k] = *(const uint4*)(wsrc + (((size_t)tap * 192 + co0 + wco) << 3));
        }
        #pragma unroll
        for (int k = 0; k < 5; ++k)
            *(uint4*)(lin + (tid + 256 * k) * 16) = xi[k];
        #pragma unroll
        for (int k = 0; k < 7; ++k)
            *(uint4*)(lw + ((wtap + 4 * k) * 65 + wco) * 16) = wi[k];
        __syncthreads();

        #pragma unroll
        for (int s = 0; s < 7; ++s) {
            bf16x8 a[4];
            #pragma unroll
            for (int m = 0; m < 4; ++m)
                a[m] = *(const bf16x8*)(lw + aoff[s] + m * 256);
            #pragma unroll
            for (int n = 0; n < 8; ++n) {
                bf16x8 bv = *(const bf16x8*)(lin + nb[n] + brow[s] +
                                             (((wn[n] + bdx[s]) & 31) << 4));
                #pragma unroll
                for (int m = 0; m < 4; ++m)
                    acc[m][n] = __builtin_amdgcn_mfma_f32_16x16x32_bf16(a[m], bv, acc[m][n], 0, 0, 0);
            }
        }
        __syncthreads();
    }

    float bv[4][4];
    #pragma unroll
    for (int m = 0; m < 4; ++m)
        #pragma unroll
        for (int r = 0; r < 4; ++r)
            bv[m][r] = bias[co0 + m * 16 + g * 4 + r];
    #pragma unroll
    for (int n = 0; n < 8; ++n) {
        int posl = wv * 128 + n * 16 + c;
        int dof = posl >> 8, rem = posl & 255;
        size_t spo = (size_t)(d0 + dof) * 1024 + (size_t)(h0 + (rem >> 5)) * 32 + (rem & 31);
        #pragma unroll
        for (int m = 0; m < 4; ++m) {
            int co = co0 + m * 16 + g * 4;
            #pragma unroll
            for (int r = 0; r < 4; ++r)
                out[((size_t)(b * NC + co + r) << 15) + spo] = acc[m][n][r] + bv[m][r];
        }
    }
}

// ---------------------------------------------------------------------------
// Fused InstanceNorm + exact GELU, in place. One block per (b,c).
// ---------------------------------------------------------------------------
__global__ __launch_bounds__(256) void inorm_gelu_kernel(float* __restrict__ buf)
{
    int c = blockIdx.x, b = blockIdx.y;
    size_t base = ((size_t)(b * NC + c)) << 15;
    int tid = threadIdx.x;
    const float4* p4 = (const float4*)(buf + base);
    float s = 0.f, q = 0.f;
    for (int i = tid; i < 8192; i += 256) {
        float4 v = p4[i];
        s += v.x + v.y + v.z + v.w;
        q += v.x * v.x + v.y * v.y + v.z * v.z + v.w * v.w;
    }
    #pragma unroll
    for (int off = 32; off > 0; off >>= 1) {
        s += __shfl_down(s, off);
        q += __shfl_down(q, off);
    }
    __shared__ float ls[4], lq[4];
    __shared__ float mv[2];
    if ((tid & 63) == 0) { ls[tid >> 6] = s; lq[tid >> 6] = q; }
    __syncthreads();
    if (tid == 0) {
        float S = ls[0] + ls[1] + ls[2] + ls[3];
        float Q = lq[0] + lq[1] + lq[2] + lq[3];
        float m = S / 32768.0f;
        float var = Q / 32768.0f - m * m;
        mv[0] = m;
        mv[1] = rsqrtf(var + 1e-5f);
    }
    __syncthreads();
    float m = mv[0], r = mv[1];
    float4* o4 = (float4*)(buf + base);
    for (int i = tid; i < 8192; i += 256) {
        float4 v = o4[i];
        v.x = gelu_f((v.x - m) * r);
        v.y = gelu_f((v.y - m) * r);
        v.z = gelu_f((v.z - m) * r);
        v.w = gelu_f((v.w - m) * r);
        o4[i] = v;
    }
}

// ---------------------------------------------------------------------------
// 1x1 conv as fp32 GEMM. Tile 64co x 128pos. EPI 1: out = x * sigmoid(.)
// ---------------------------------------------------------------------------
template<int EPI>
__global__ __launch_bounds__(256) void gemm_kernel(const float* __restrict__ in,
        const float* __restrict__ wmat, const float* __restrict__ bias,
        float* __restrict__ out, const float* __restrict__ xin, int M)
{
    __shared__ __align__(16) float At[16][68];
    __shared__ __align__(16) float Bt[16][128];
    int co0 = blockIdx.x * 64;
    int p0  = blockIdx.y * 128;
    int b   = blockIdx.z;
    int tid = threadIdx.x;
    int pg  = tid & 31;
    int cg  = tid >> 5;
    float acc[8][4];
    #pragma unroll
    for (int i = 0; i < 8; ++i)
        #pragma unroll
        for (int j = 0; j < 4; ++j) acc[i][j] = 0.f;

    const float* inb = in + (((size_t)b * NC) << 15);
    for (int k0 = 0; k0 < NC; k0 += 16) {
        #pragma unroll
        for (int i = 0; i < 4; ++i) {
            int e = tid + 256 * i;
            int kl = e & 15, cl = e >> 4;
            At[kl][cl] = wmat[(size_t)(co0 + cl) * NC + k0 + kl];
        }
        #pragma unroll
        for (int i = 0; i < 2; ++i) {
            int e = tid + 256 * i;
            int plc = (e & 31) << 2;
            int kl = e >> 5;
            *(float4*)&Bt[kl][plc] =
                *(const float4*)&inb[((size_t)(k0 + kl) << 15) + p0 + plc];
        }
        __syncthreads();
        #pragma unroll
        for (int k = 0; k < 16; ++k) {
            float a[8], bb[4];
            *(float4*)&a[0] = *(float4*)&At[k][cg * 8];
            *(float4*)&a[4] = *(float4*)&At[k][cg * 8 + 4];
            *(float4*)&bb[0] = *(float4*)&Bt[k][pg * 4];
            #pragma unroll
            for (int i = 0; i < 8; ++i)
                #pragma unroll
                for (int j = 0; j < 4; ++j)
                    acc[i][j] += a[i] * bb[j];
        }
        __syncthreads();
    }

    #pragma unroll
    for (int i = 0; i < 8; ++i) {
        int co = co0 + cg * 8 + i;
        float bvv = bias[co];
        size_t obase = (((size_t)(b * M + co)) << 15) + p0 + pg * 4;
        float4 r;
        r.x = acc[i][0] + bvv; r.y = acc[i][1] + bvv;
        r.z = acc[i][2] + bvv; r.w = acc[i][3] + bvv;
        if (EPI == 1) {
            float4 xv = *(const float4*)&xin[obase];
            r.x = xv.x / (1.0f + expf(-r.x));
            r.y = xv.y / (1.0f + expf(-r.y));
            r.z = xv.z / (1.0f + expf(-r.z));
            r.w = xv.w / (1.0f + expf(-r.w));
        }
        *(float4*)&out[obase] = r;
    }
}

// ---------------------------------------------------------------------------
// Transposes to seq-contiguous layouts. 32x33 LDS tile, coalesced both sides.
// t0: qt[b][ch][h*32+w][d] = qkv[b][ch][d*1024+h*32+w]   (axis depth)
// t1: qt[b][ch][d*32+w][h] = qkv[b][ch][d*1024+h*32+w]   (axis height)
// ---------------------------------------------------------------------------
__global__ __launch_bounds__(256) void t0_kernel(const float* __restrict__ in,
                                                 float* __restrict__ out)
{
    __shared__ float lds[32][33];
    int h = blockIdx.x, ch = blockIdx.y, b = blockIdx.z;
    size_t cb = ((size_t)(b * 576 + ch)) << 15;
    int t = threadIdx.x;
    int c0 = t & 31, g = t >> 5;
    #pragma unroll
    for (int i = 0; i < 4; ++i) {
        int d = g + 8 * i;
        lds[d][c0] = in[cb + d * 1024 + h * 32 + c0];
    }
    __syncthreads();
    #pragma unroll
    for (int i = 0; i < 4; ++i) {
        int w = g + 8 * i;
        out[cb + (h * 32 + w) * 32 + c0] = lds[c0][w];
    }
}

__global__ __launch_bounds__(256) void t1_kernel(const float* __restrict__ in,
                                                 float* __restrict__ out)
{
    __shared__ float lds[32][33];
    int d = blockIdx.x, ch = blockIdx.y, b = blockIdx.z;
    size_t cb = ((size_t)(b * 576 + ch)) << 15;
    int t = threadIdx.x;
    int c0 = t & 31, g = t >> 5;
    #pragma unroll
    for (int i = 0; i < 4; ++i) {
        int h = g + 8 * i;
        lds[h][c0] = in[cb + d * 1024 + h * 32 + c0];
    }
    __syncthreads();
    #pragma unroll
    for (int i = 0; i < 4; ++i) {
        int w = g + 8 * i;
        out[cb + (d * 32 + w) * 32 + c0] = lds[c0][w];
    }
}

// inv0: buf[b][ch][d*1024+h*32+w] += o[b][ch][(h*32+w)*32+d]   (ch < 192)
// inv1: buf[b][ch][d*1024+h*32+w] += o[b][ch][(d*32+w)*32+h]
__global__ __launch_bounds__(256) void inv0_kernel(const float* __restrict__ o,
                                                   float* __restrict__ buf)
{
    __shared__ float lds[32][33];
    int h = blockIdx.x, ch = blockIdx.y, b = blockIdx.z;
    size_t cb = ((size_t)(b * NC + ch)) << 15;
    int t = threadIdx.x;
    int c0 = t & 31, g = t >> 5;
    #pragma unroll
    for (int i = 0; i < 4; ++i) {
        int w = g + 8 * i;
        lds[w][c0] = o[cb + (h * 32 + w) * 32 + c0];   // c0 = d
    }
    __syncthreads();
    #pragma unroll
    for (int i = 0; i < 4; ++i) {
        int d = g + 8 * i;
        buf[cb + d * 1024 + h * 32 + c0] += lds[c0][d];   // c0 = w
    }
}

__global__ __launch_bounds__(256) void inv1_kernel(const float* __restrict__ o,
                                                   float* __restrict__ buf)
{
    __shared__ float lds[32][33];
    int d = blockIdx.x, ch = blockIdx.y, b = blockIdx.z;
    size_t cb = ((size_t)(b * NC + ch)) << 15;
    int t = threadIdx.x;
    int c0 = t & 31, g = t >> 5;
    #pragma unroll
    for (int i = 0; i < 4; ++i) {
        int w = g + 8 * i;
        lds[w][c0] = o[cb + (d * 32 + w) * 32 + c0];   // c0 = h
    }
    __syncthreads();
    #pragma unroll
    for (int i = 0; i < 4; ++i) {
        int h = g + 8 * i;
        buf[cb + d * 1024 + h * 32 + c0] += lds[c0][h];   // c0 = w
    }
}

// ---------------------------------------------------------------------------
// Axial attention on seq-contiguous layout [b][ch][line][seq], fully coalesced.
// One wave per (b, line, head). pos_attn bias cancels (softmax shift-invar).
// ---------------------------------------------------------------------------
__global__ __launch_bounds__(64) void attn_seq_kernel(const float* __restrict__ qkv,
        const float* __restrict__ Rbuf, float* __restrict__ outp, int axis)
{
    __shared__ __align__(16) float rq[32][28];
    __shared__ __align__(16) float rk[32][28];
    __shared__ __align__(16) float vv[32][28];
    __shared__ __align__(16) float pl[32][36];

    int line = blockIdx.x;
    int h    = blockIdx.y;
    int b    = blockIdx.z;
    int lane = threadIdx.x;
    int m  = lane & 31;
    int df = lane >> 5;

    size_t qb = (((size_t)b * 576) << 15) + (size_t)line * 32;

    float Rm[9];
    {
        const float* rp = Rbuf + (((size_t)axis * 8 + h) * 32 + m) * 9;
        #pragma unroll
        for (int i = 0; i < 9; ++i) Rm[i] = rp[i];
    }
    const float scale = 0.20412414523193154f;

    #pragma unroll
    for (int v = 0; v < 4; ++v) {
        int d0 = (df * 4 + v) * 3;
        size_t cq = qb + (((size_t)(h * HDIM + d0)) << 15) + m;
        float q0 = qkv[cq];
        float q1 = qkv[cq + (1u << 15)];
        float q2 = qkv[cq + (2u << 15)];
        rq[m][d0 + 0] = (Rm[0] * q0 + Rm[1] * q1 + Rm[2] * q2) * scale;
        rq[m][d0 + 1] = (Rm[3] * q0 + Rm[4] * q1 + Rm[5] * q2) * scale;
        rq[m][d0 + 2] = (Rm[6] * q0 + Rm[7] * q1 + Rm[8] * q2) * scale;
        size_t ck = qb + (((size_t)(NC + h * HDIM + d0)) << 15) + m;
        float k0 = qkv[ck];
        float k1 = qkv[ck + (1u << 15)];
        float k2 = qkv[ck + (2u << 15)];
        rk[m][d0 + 0] = Rm[0] * k0 + Rm[1] * k1 + Rm[2] * k2;
        rk[m][d0 + 1] = Rm[3] * k0 + Rm[4] * k1 + Rm[5] * k2;
        rk[m][d0 + 2] = Rm[6] * k0 + Rm[7] * k1 + Rm[8] * k2;
    }
    #pragma unroll
    for (int i = 0; i < 12; ++i) {
        int d = df * 12 + i;
        vv[m][d] = qkv[qb + (((size_t)(2 * NC + h * HDIM + d)) << 15) + m];
    }
    __syncthreads();

    float qrow[24];
    #pragma unroll
    for (int i = 0; i < 6; ++i)
        *(float4*)&qrow[i * 4] = *(float4*)&rq[m][i * 4];
    float pv[16];
    float mymax = -1e30f;
    #pragma unroll
    for (int j = 0; j < 16; ++j) {
        int mm = df * 16 + j;
        float s = 0.f;
        #pragma unroll
        for (int d = 0; d < 24; d += 4) {
            float4 kk = *(float4*)&rk[mm][d];
            s += qrow[d] * kk.x + qrow[d + 1] * kk.y + qrow[d + 2] * kk.z + qrow[d + 3] * kk.w;
        }
        pv[j] = s;
        mymax = fmaxf(mymax, s);
    }
    float rmax = fmaxf(mymax, __shfl_xor(mymax, 32));
    float mysum = 0.f;
    #pragma unroll
    for (int j = 0; j < 16; ++j) {
        pv[j] = expf(pv[j] - rmax);
        mysum += pv[j];
    }
    float rsum = mysum + __shfl_xor(mysum, 32);
    float inv = 1.0f / rsum;
    #pragma unroll
    for (int j = 0; j < 16; ++j) pl[m][df * 16 + j] = pv[j] * inv;
    __syncthreads();

    float prow[32];
    #pragma unroll
    for (int i = 0; i < 8; ++i)
        *(float4*)&prow[i * 4] = *(float4*)&pl[m][i * 4];
    float o[12];
    #pragma unroll
    for (int i = 0; i < 12; ++i) o[i] = 0.f;
    #pragma unroll
    for (int mm = 0; mm < 32; ++mm) {
        float p = prow[mm];
        float4 v0 = *(float4*)&vv[mm][df * 12];
        float4 v1 = *(float4*)&vv[mm][df * 12 + 4];
        float4 v2 = *(float4*)&vv[mm][df * 12 + 8];
        o[0] += p * v0.x; o[1]  += p * v0.y; o[2]  += p * v0.z; o[3]  += p * v0.w;
        o[4] += p * v1.x; o[5]  += p * v1.y; o[6]  += p * v1.z; o[7]  += p * v1.w;
        o[8] += p * v2.x; o[9]  += p * v2.y; o[10] += p * v2.z; o[11] += p * v2.w;
    }
    size_t ob = (((size_t)b * NC) << 15) + (size_t)line * 32 + m;
    #pragma unroll
    for (int i = 0; i < 12; ++i)
        outp[ob + (((size_t)(h * HDIM + df * 12 + i)) << 15)] = o[i];
}

// ---------------------------------------------------------------------------
// Fallback (R2) attention: strided reads from canonical layout, with accum.
// ---------------------------------------------------------------------------
__global__ __launch_bounds__(64) void attn_kernel(const float* __restrict__ qkv,
        const float* __restrict__ Rbuf, float* __restrict__ outacc,
        int axis, int accum)
{
    __shared__ __align__(16) float rq[32][28];
    __shared__ __align__(16) float rk[32][28];
    __shared__ __align__(16) float vv[32][28];
    __shared__ __align__(16) float pl[32][36];

    int o12 = blockIdx.x;
    int h   = blockIdx.y;
    int b   = blockIdx.z;
    int o1 = o12 >> 5, o2 = o12 & 31;
    int lane = threadIdx.x;
    int m  = lane & 31;
    int df = lane >> 5;

    int pbase, pstride;
    if (axis == 0)      { pbase = (o1 << 5) + o2;        pstride = 1024; }
    else if (axis == 1) { pbase = (o1 << 10) + o2;       pstride = 32; }
    else                { pbase = (o1 << 10) + (o2 << 5); pstride = 1; }

    size_t qb = ((size_t)b * 576) << 15;
    int p_m = pbase + m * pstride;

    float Rm[9];
    {
        const float* rp = Rbuf + (((size_t)axis * 8 + h) * 32 + m) * 9;
        #pragma unroll
        for (int i = 0; i < 9; ++i) Rm[i] = rp[i];
    }
    const float scale = 0.20412414523193154f;

    #pragma unroll
    for (int v = 0; v < 4; ++v) {
        int d0 = (df * 4 + v) * 3;
        size_t cq = qb + (((size_t)(h * HDIM + d0)) << 15) + p_m;
        float q0 = qkv[cq];
        float q1 = qkv[cq + (1u << 15)];
        float q2 = qkv[cq + (2u << 15)];
        rq[m][d0 + 0] = (Rm[0] * q0 + Rm[1] * q1 + Rm[2] * q2) * scale;
        rq[m][d0 + 1] = (Rm[3] * q0 + Rm[4] * q1 + Rm[5] * q2) * scale;
        rq[m][d0 + 2] = (Rm[6] * q0 + Rm[7] * q1 + Rm[8] * q2) * scale;
        size_t ck = qb + (((size_t)(NC + h * HDIM + d0)) << 15) + p_m;
        float k0 = qkv[ck];
        float k1 = qkv[ck + (1u << 15)];
        float k2 = qkv[ck + (2u << 15)];
        rk[m][d0 + 0] = Rm[0] * k0 + Rm[1] * k1 + Rm[2] * k2;
        rk[m][d0 + 1] = Rm[3] * k0 + Rm[4] * k1 + Rm[5] * k2;
        rk[m][d0 + 2] = Rm[6] * k0 + Rm[7] * k1 + Rm[8] * k2;
    }
    #pragma unroll
    for (int i = 0; i < 12; ++i) {
        int d = df * 12 + i;
        vv[m][d] = qkv[qb + (((size_t)(2 * NC + h * HDIM + d)) << 15) + p_m];
    }
    __syncthreads();

    float qrow[24];
    #pragma unroll
    for (int i = 0; i < 6; ++i)
        *(float4*)&qrow[i * 4] = *(float4*)&rq[m][i * 4];
    float pv[16];
    float mymax = -1e30f;
    #pragma unroll
    for (int j = 0; j < 16; ++j) {
        int mm = df * 16 + j;
        float s = 0.f;
        #pragma unroll
        for (int d = 0; d < 24; d += 4) {
            float4 kk = *(float4*)&rk[mm][d];
            s += qrow[d] * kk.x + qrow[d + 1] * kk.y + qrow[d + 2] * kk.z + qrow[d + 3] * kk.w;
        }
        pv[j] = s;
        mymax = fmaxf(mymax, s);
    }
    float rmax = fmaxf(mymax, __shfl_xor(mymax, 32));
    float mysum = 0.f;
    #pragma unroll
    for (int j = 0; j < 16; ++j) {
        pv[j] = expf(pv[j] - rmax);
        mysum += pv[j];
    }
    float rsum = mysum + __shfl_xor(mysum, 32);
    float inv = 1.0f / rsum;
    #pragma unroll
    for (int j = 0; j < 16; ++j) pl[m][df * 16 + j] = pv[j] * inv;
    __syncthreads();

    float prow[32];
    #pragma unroll
    for (int i = 0; i < 8; ++i)
        *(float4*)&prow[i * 4] = *(float4*)&pl[m][i * 4];
    float o[12];
    #pragma unroll
    for (int i = 0; i < 12; ++i) o[i] = 0.f;
    #pragma unroll
    for (int mm = 0; mm < 32; ++mm) {
        float p = prow[mm];
        float4 v0 = *(float4*)&vv[mm][df * 12];
        float4 v1 = *(float4*)&vv[mm][df * 12 + 4];
        float4 v2 = *(float4*)&vv[mm][df * 12 + 8];
        o[0] += p * v0.x; o[1]  += p * v0.y; o[2]  += p * v0.z; o[3]  += p * v0.w;
        o[4] += p * v1.x; o[5]  += p * v1.y; o[6]  += p * v1.z; o[7]  += p * v1.w;
        o[8] += p * v2.x; o[9]  += p * v2.y; o[10] += p * v2.z; o[11] += p * v2.w;
    }
    size_t ob = ((size_t)(b * NC)) << 15;
    int p_l = pbase + m * pstride;
    #pragma unroll
    for (int i = 0; i < 12; ++i) {
        size_t a = ob + (((size_t)(h * HDIM + df * 12 + i)) << 15) + p_l;
        if (accum) outacc[a] += o[i];
        else       outacc[a] = o[i];
    }
}

// ---------------------------------------------------------------------------
extern "C" void kernel_launch(void* const* d_in, const int* in_sizes, int n_in,
                              void* d_out, int out_size, void* d_ws, size_t ws_size,
                              hipStream_t stream)
{
    (void)in_sizes; (void)n_in; (void)out_size;
    const float* x      = (const float*)d_in[0];
    const float* pos    = (const float*)d_in[1];
    const float* lp1_w  = (const float*)d_in[2];
    const float* lp1_b  = (const float*)d_in[3];
    const float* lp2_w  = (const float*)d_in[4];
    const float* lp2_b  = (const float*)d_in[5];
    const float* m1_w   = (const float*)d_in[6];
    const float* m1_b   = (const float*)d_in[7];
    const float* m2_w   = (const float*)d_in[8];
    const float* m2_b   = (const float*)d_in[9];
    // d_in[10]=pa_w, d_in[11]=pa_b: per-query softmax bias, cancels -> unused
    const float* qkv_w  = (const float*)d_in[12];
    const float* qkv_b  = (const float*)d_in[13];
    const float* A_d    = (const float*)d_in[14];
    const float* A_h    = (const float*)d_in[15];
    const float* A_w    = (const float*)d_in[16];
    const float* proj_w = (const float*)d_in[17];
    const float* proj_b = (const float*)d_in[18];

    float* ws   = (float*)d_ws;
    float* Rbuf = ws;                       // 8192 floats
    float* buf1 = ws + 8192;                // A: 12,582,912 floats
    float* buf2 = buf1 + 12582912;          // B: 12,582,912 floats
    float* qkvb = buf2 + 12582912;          // C: 37,748,736 floats
    float* qtA  = qkvb + 37748736;          // D: 37,748,736 floats (big path only)
    // conv-phase aliases (B region onward, dead later):
    ushort* xb2 = (ushort*)buf2;            // 50.3 MB
    ushort* wb2 = xb2 + 25165824;           //  4.1 MB (spills into C, fine)

    const size_t need_big = (size_t)(8192 + 2 * 12582912 + 2 * 37748736) * 4;
    bool big = ws_size >= need_big;

    rot_kernel<<<dim3(3), 256, 0, stream>>>(A_d, A_h, A_w, Rbuf);
    xcvt_kernel<<<dim3(512, 2), 256, 0, stream>>>(pos, xb2);
    wcvt_kernel<<<dim3(1008), 256, 0, stream>>>(lp1_w, wb2);
    conv3_mfma<<<dim3(3, 64, 2), 256, 0, stream>>>(xb2, wb2, lp1_b, buf1);

    inorm_gelu_kernel<<<dim3(192, 2), 256, 0, stream>>>(buf1);
    gemm_kernel<0><<<dim3(3, 256, 2), 256, 0, stream>>>(buf1, lp2_w, lp2_b, buf2, nullptr, 192);
    gemm_kernel<0><<<dim3(3, 256, 2), 256, 0, stream>>>(buf2, m1_w, m1_b, buf1, nullptr, 192);
    inorm_gelu_kernel<<<dim3(192, 2), 256, 0, stream>>>(buf1);
    gemm_kernel<1><<<dim3(3, 256, 2), 256, 0, stream>>>(buf1, m2_w, m2_b, buf2, x, 192);
    gemm_kernel<0><<<dim3(9, 256, 2), 256, 0, stream>>>(buf2, qkv_w, qkv_b, qkvb, nullptr, 576);

    if (big) {
        // x_mod (buf2) dead now -> reuse as attn-output staging
        float* oA = buf2;
        // axis 2 (width): qkvb is already [ch][line=d*32+h][seq=w]
        attn_seq_kernel<<<dim3(1024, 8, 2), 64, 0, stream>>>(qkvb, Rbuf, buf1, 2);
        // axis 0 (depth)
        t0_kernel<<<dim3(32, 576, 2), 256, 0, stream>>>(qkvb, qtA);
        attn_seq_kernel<<<dim3(1024, 8, 2), 64, 0, stream>>>(qtA, Rbuf, oA, 0);
        inv0_kernel<<<dim3(32, 192, 2), 256, 0, stream>>>(oA, buf1);
        // axis 1 (height)
        t1_kernel<<<dim3(32, 576, 2), 256, 0, stream>>>(qkvb, qtA);
        attn_seq_kernel<<<dim3(1024, 8, 2), 64, 0, stream>>>(qtA, Rbuf, oA, 1);
        inv1_kernel<<<dim3(32, 192, 2), 256, 0, stream>>>(oA, buf1);
    } else {
        attn_kernel<<<dim3(1024, 8, 2), 64, 0, stream>>>(qkvb, Rbuf, buf1, 0, 0);
        attn_kernel<<<dim3(1024, 8, 2), 64, 0, stream>>>(qkvb, Rbuf, buf1, 1, 1);
        attn_kernel<<<dim3(1024, 8, 2), 64, 0, stream>>>(qkvb, Rbuf, buf1, 2, 1);
    }
    gemm_kernel<0><<<dim3(3, 256, 2), 256, 0, stream>>>(buf1, proj_w, proj_b, (float*)d_out, nullptr, 192);
}

// Round 4
// 1281.058 us; speedup vs baseline: 1.3583x; 1.3583x over previous
//
#include <hip/hip_runtime.h>
#include <hip/hip_bf16.h>
#include <math.h>

#define SD 32
#define NSPA 32768          // 32^3
#define NC 192
#define NB 2
#define NHD 8
#define HDIM 24

typedef __bf16 bf16x8 __attribute__((ext_vector_type(8)));
typedef float f32x4 __attribute__((ext_vector_type(4)));

__device__ __forceinline__ float gelu_f(float x) {
    return 0.5f * x * (1.0f + erff(x * 0.70710678118654752f));
}

__device__ __forceinline__ ushort bfr(float x) {   // fp32 -> bf16 bits, RNE
    unsigned u = __float_as_uint(x);
    unsigned r = (u + 0x7fffu + ((u >> 16) & 1u)) >> 16;
    return (ushort)r;
}

// ---------------------------------------------------------------------------
// Rotation matrices R[axis][h][l][3][3] (Rodrigues, numeric K@K like ref)
// ---------------------------------------------------------------------------
__global__ void rot_kernel(const float* __restrict__ Ad, const float* __restrict__ Ah,
                           const float* __restrict__ Aw, float* __restrict__ R)
{
    int idx = blockIdx.x * 256 + threadIdx.x;   // 0..767
    if (idx >= 768) return;
    int l = idx & 31;
    int h = (idx >> 5) & 7;
    int axis = idx >> 8;
    const float* A = (axis == 0) ? Ad : ((axis == 1) ? Ah : Aw);
    int comp = (axis == 0) ? 2 : ((axis == 1) ? 1 : 0);
    float p = -1.0f + 2.0f * (float)l / 31.0f;
    float w0 = p * A[h * 9 + 0 * 3 + comp];
    float w1 = p * A[h * 9 + 1 * 3 + comp];
    float w2 = p * A[h * 9 + 2 * 3 + comp];
    float th = sqrtf(w0 * w0 + w1 * w1 + w2 * w2);
    th = fmaxf(th, 1e-8f);
    float ux = w0 / th, uy = w1 / th, uz = w2 / th;
    float K[3][3] = {{0.f, -uz, uy}, {uz, 0.f, -ux}, {-uy, ux, 0.f}};
    float K2[3][3];
    #pragma unroll
    for (int i = 0; i < 3; ++i)
        #pragma unroll
        for (int j = 0; j < 3; ++j) {
            float s = 0.f;
            #pragma unroll
            for (int k = 0; k < 3; ++k) s += K[i][k] * K[k][j];
            K2[i][j] = s;
        }
    float s = sinf(th), c = cosf(th);
    float* out = R + (size_t)idx * 9;
    #pragma unroll
    for (int i = 0; i < 3; ++i)
        #pragma unroll
        for (int j = 0; j < 3; ++j)
            out[i * 3 + j] = ((i == j) ? 1.0f : 0.0f) + s * K[i][j] + (1.0f - c) * K2[i][j];
}

// ---------------------------------------------------------------------------
// Input repack: pos_emb fp32 -> bf16 hi/lo, [b][cc48][pos][8]
// ---------------------------------------------------------------------------
__global__ __launch_bounds__(256) void xcvt_kernel(const float* __restrict__ in,
                                                   ushort* __restrict__ xb)
{
    __shared__ float lds[192][66];
    int t = threadIdx.x;
    int pos0 = blockIdx.x * 64;
    int b = blockIdx.y;
    #pragma unroll 4
    for (int i = 0; i < 48; ++i) {
        int idx = t + 256 * i;
        int ci = idx >> 6, col = idx & 63;
        lds[ci][col] = in[((size_t)(b * NC + ci) << 15) + pos0 + col];
    }
    __syncthreads();
    int p = t & 63;
    int ccb = t >> 6;
    #pragma unroll
    for (int i = 0; i < 12; ++i) {
        int cc = i * 4 + ccb;
        unsigned ov[4];
        #pragma unroll
        for (int k = 0; k < 4; ++k) {
            float x = lds[cc * 4 + k][p];
            ushort hi = bfr(x);
            float hif = __uint_as_float((unsigned)hi << 16);
            ushort lo = bfr(x - hif);
            ov[k] = (unsigned)hi | ((unsigned)lo << 16);
        }
        *(uint4*)(xb + ((((size_t)(b * 48 + cc)) << 15) + pos0 + p) * 8) = *(uint4*)ov;
    }
}

// ---------------------------------------------------------------------------
// Weight repack: lp1_w fp32 [co][ci][27] -> wb bf16 [cc48][tap28][co192][8]
// ---------------------------------------------------------------------------
__global__ __launch_bounds__(256) void wcvt_kernel(const float* __restrict__ wgt,
                                                   ushort* __restrict__ wb)
{
    int slot = blockIdx.x * 256 + threadIdx.x;
    if (slot >= 48 * 28 * 192) return;
    int cc = slot / (28 * 192);
    int r = slot % (28 * 192);
    int tap = r / 192, co = r % 192;
    unsigned ov[4];
    #pragma unroll
    for (int k = 0; k < 4; ++k) {
        int ci = cc * 4 + k;
        float w = (tap < 27) ? wgt[((size_t)co * NC + ci) * 27 + tap] : 0.f;
        ushort wv = bfr(w);
        ov[k] = (unsigned)wv | ((unsigned)wv << 16);
    }
    *(uint4*)(wb + (size_t)slot * 8) = *(uint4*)ov;
}

// ---------------------------------------------------------------------------
// Circular 3x3x3 conv as implicit-GEMM MFMA (bf16, hi/lo split input).
// ---------------------------------------------------------------------------
#define LIN_BYTES (4 * 10 * 32 * 16)   // 20480
#define LW_BYTES  (28 * 65 * 16)       // 29120

__global__ __launch_bounds__(256, 2) void conv3_mfma(
        const ushort* __restrict__ xb, const ushort* __restrict__ wb,
        const float* __restrict__ bias, float* __restrict__ out)
{
    __shared__ __align__(16) char smem[LIN_BYTES + LW_BYTES];
    char* lin = smem;
    char* lw  = smem + LIN_BYTES;
    int tid = threadIdx.x;
    int co0 = blockIdx.x * 64;
    int sp  = blockIdx.y;               // 0..63
    int b   = blockIdx.z;
    int d0 = (sp >> 2) * 2;
    int h0 = (sp & 3) * 8;
    int lane = tid & 63, wv = tid >> 6;
    int g = lane >> 4, c = lane & 15;

    int aoff[7], brow[7], bdx[7];
    #pragma unroll
    for (int s = 0; s < 7; ++s) {
        int tap = 4 * s + g;
        aoff[s] = (tap * 65 + c) * 16;
        int tc = tap > 26 ? 26 : tap;
        int dz = tc / 9, r = tc % 9, dy = r / 3, dx = r % 3;
        brow[s] = (dz * 10 + dy) * 512;
        bdx[s] = dx - 1;
    }
    int nb[8], wn[8];
    #pragma unroll
    for (int n = 0; n < 8; ++n) {
        int posl = wv * 128 + n * 16 + c;
        int dof = posl >> 8, rem = posl & 255;
        nb[n] = dof * 5120 + (rem >> 5) * 512;
        wn[n] = rem & 31;
    }

    int xoff[5];
    #pragma unroll
    for (int k = 0; k < 5; ++k) {
        int i = tid + 256 * k;
        int dz = i / 320, r2 = i % 320, hh = r2 >> 5, ww = r2 & 31;
        int dd = (d0 + dz + 31) & 31, hg = (h0 + hh + 31) & 31;
        xoff[k] = (dd << 10) + (hg << 5) + ww;
    }
    int wco = tid & 63;
    int wtap = tid >> 6;

    f32x4 acc[4][8];
    #pragma unroll
    for (int m = 0; m < 4; ++m)
        #pragma unroll
        for (int n = 0; n < 8; ++n)
            acc[m][n] = (f32x4){0.f, 0.f, 0.f, 0.f};

    const size_t xbb = ((size_t)b * 48) << 15;

    for (int cc = 0; cc < 48; ++cc) {
        const ushort* xsrc = xb + ((xbb + ((size_t)cc << 15)) << 3);
        uint4 xi[5];
        #pragma unroll
        for (int k = 0; k < 5; ++k)
            xi[k] = *(const uint4*)(xsrc + ((size_t)xoff[k] << 3));
        const ushort* wsrc = wb + (((size_t)cc * 28 * 192) << 3);
        uint4 wi[7];
        #pragma unroll
        for (int k = 0; k < 7; ++k) {
            int tap = wtap + 4 * k;
            wi[k] = *(const uint4*)(wsrc + (((size_t)tap * 192 + co0 + wco) << 3));
        }
        #pragma unroll
        for (int k = 0; k < 5; ++k)
            *(uint4*)(lin + (tid + 256 * k) * 16) = xi[k];
        #pragma unroll
        for (int k = 0; k < 7; ++k)
            *(uint4*)(lw + ((wtap + 4 * k) * 65 + wco) * 16) = wi[k];
        __syncthreads();

        #pragma unroll
        for (int s = 0; s < 7; ++s) {
            bf16x8 a[4];
            #pragma unroll
            for (int m = 0; m < 4; ++m)
                a[m] = *(const bf16x8*)(lw + aoff[s] + m * 256);
            #pragma unroll
            for (int n = 0; n < 8; ++n) {
                bf16x8 bv = *(const bf16x8*)(lin + nb[n] + brow[s] +
                                             (((wn[n] + bdx[s]) & 31) << 4));
                #pragma unroll
                for (int m = 0; m < 4; ++m)
                    acc[m][n] = __builtin_amdgcn_mfma_f32_16x16x32_bf16(a[m], bv, acc[m][n], 0, 0, 0);
            }
        }
        __syncthreads();
    }

    float bv[4][4];
    #pragma unroll
    for (int m = 0; m < 4; ++m)
        #pragma unroll
        for (int r = 0; r < 4; ++r)
            bv[m][r] = bias[co0 + m * 16 + g * 4 + r];
    #pragma unroll
    for (int n = 0; n < 8; ++n) {
        int posl = wv * 128 + n * 16 + c;
        int dof = posl >> 8, rem = posl & 255;
        size_t spo = (size_t)(d0 + dof) * 1024 + (size_t)(h0 + (rem >> 5)) * 32 + (rem & 31);
        #pragma unroll
        for (int m = 0; m < 4; ++m) {
            int co = co0 + m * 16 + g * 4;
            #pragma unroll
            for (int r = 0; r < 4; ++r)
                out[((size_t)(b * NC + co + r) << 15) + spo] = acc[m][n][r] + bv[m][r];
        }
    }
}

// ---------------------------------------------------------------------------
// Fused InstanceNorm + exact GELU, in place. One block per (b,c).
// ---------------------------------------------------------------------------
__global__ __launch_bounds__(256) void inorm_gelu_kernel(float* __restrict__ buf)
{
    int c = blockIdx.x, b = blockIdx.y;
    size_t base = ((size_t)(b * NC + c)) << 15;
    int tid = threadIdx.x;
    const float4* p4 = (const float4*)(buf + base);
    float s = 0.f, q = 0.f;
    for (int i = tid; i < 8192; i += 256) {
        float4 v = p4[i];
        s += v.x + v.y + v.z + v.w;
        q += v.x * v.x + v.y * v.y + v.z * v.z + v.w * v.w;
    }
    #pragma unroll
    for (int off = 32; off > 0; off >>= 1) {
        s += __shfl_down(s, off);
        q += __shfl_down(q, off);
    }
    __shared__ float ls[4], lq[4];
    __shared__ float mv[2];
    if ((tid & 63) == 0) { ls[tid >> 6] = s; lq[tid >> 6] = q; }
    __syncthreads();
    if (tid == 0) {
        float S = ls[0] + ls[1] + ls[2] + ls[3];
        float Q = lq[0] + lq[1] + lq[2] + lq[3];
        float m = S / 32768.0f;
        float var = Q / 32768.0f - m * m;
        mv[0] = m;
        mv[1] = rsqrtf(var + 1e-5f);
    }
    __syncthreads();
    float m = mv[0], r = mv[1];
    float4* o4 = (float4*)(buf + base);
    for (int i = tid; i < 8192; i += 256) {
        float4 v = o4[i];
        v.x = gelu_f((v.x - m) * r);
        v.y = gelu_f((v.y - m) * r);
        v.z = gelu_f((v.z - m) * r);
        v.w = gelu_f((v.w - m) * r);
        o4[i] = v;
    }
}

// ---------------------------------------------------------------------------
// 1x1 conv as fp32 GEMM. Tile 64co x 128pos. EPI 1: out = x * sigmoid(.)
// ---------------------------------------------------------------------------
template<int EPI>
__global__ __launch_bounds__(256) void gemm_kernel(const float* __restrict__ in,
        const float* __restrict__ wmat, const float* __restrict__ bias,
        float* __restrict__ out, const float* __restrict__ xin, int M)
{
    __shared__ __align__(16) float At[16][68];
    __shared__ __align__(16) float Bt[16][128];
    int co0 = blockIdx.x * 64;
    int p0  = blockIdx.y * 128;
    int b   = blockIdx.z;
    int tid = threadIdx.x;
    int pg  = tid & 31;
    int cg  = tid >> 5;
    float acc[8][4];
    #pragma unroll
    for (int i = 0; i < 8; ++i)
        #pragma unroll
        for (int j = 0; j < 4; ++j) acc[i][j] = 0.f;

    const float* inb = in + (((size_t)b * NC) << 15);
    for (int k0 = 0; k0 < NC; k0 += 16) {
        #pragma unroll
        for (int i = 0; i < 4; ++i) {
            int e = tid + 256 * i;
            int kl = e & 15, cl = e >> 4;
            At[kl][cl] = wmat[(size_t)(co0 + cl) * NC + k0 + kl];
        }
        #pragma unroll
        for (int i = 0; i < 2; ++i) {
            int e = tid + 256 * i;
            int plc = (e & 31) << 2;
            int kl = e >> 5;
            *(float4*)&Bt[kl][plc] =
                *(const float4*)&inb[((size_t)(k0 + kl) << 15) + p0 + plc];
        }
        __syncthreads();
        #pragma unroll
        for (int k = 0; k < 16; ++k) {
            float a[8], bb[4];
            *(float4*)&a[0] = *(float4*)&At[k][cg * 8];
            *(float4*)&a[4] = *(float4*)&At[k][cg * 8 + 4];
            *(float4*)&bb[0] = *(float4*)&Bt[k][pg * 4];
            #pragma unroll
            for (int i = 0; i < 8; ++i)
                #pragma unroll
                for (int j = 0; j < 4; ++j)
                    acc[i][j] += a[i] * bb[j];
        }
        __syncthreads();
    }

    #pragma unroll
    for (int i = 0; i < 8; ++i) {
        int co = co0 + cg * 8 + i;
        float bvv = bias[co];
        size_t obase = (((size_t)(b * M + co)) << 15) + p0 + pg * 4;
        float4 r;
        r.x = acc[i][0] + bvv; r.y = acc[i][1] + bvv;
        r.z = acc[i][2] + bvv; r.w = acc[i][3] + bvv;
        if (EPI == 1) {
            float4 xv = *(const float4*)&xin[obase];
            r.x = xv.x / (1.0f + expf(-r.x));
            r.y = xv.y / (1.0f + expf(-r.y));
            r.z = xv.z / (1.0f + expf(-r.z));
            r.w = xv.w / (1.0f + expf(-r.w));
        }
        *(float4*)&out[obase] = r;
    }
}

// ---------------------------------------------------------------------------
// Fused axial attention: transpose-in-LDS, one dispatch per axis, no extra ws.
// Block = (b, head, o, slab): 8 lines x 32 seq. 256 threads; thread (l,m)
// stages+rotates its q/k row and converts v to bf16; wave wv computes lines
// 2wv, 2wv+1 exactly like the reference kernel (softmax halves exchanged via
// shfl_xor instead of LDS). Output staged in LDS (aliases rqL) and written
// coalesced. XCD-grouped blockIdx so sibling slabs share L2 lines.
// pos_attn bias cancels (constant along softmax axis).
// ---------------------------------------------------------------------------
template<int AXIS, int ACCUM>
__global__ __launch_bounds__(256, 2) void attn_fused(const float* __restrict__ qkv,
        const float* __restrict__ Rbuf, float* __restrict__ outb)
{
    __shared__ __align__(16) float  rqL[32][8][24];   // also reused as oL
    __shared__ __align__(16) float  rkL[32][8][24];
    __shared__ __align__(16) ushort vL[32][8][24];

    int bid = blockIdx.x;
    int cxc = bid & 7;
    int r   = bid >> 3;
    int slab = r & 3;
    int tup  = ((r >> 2) << 3) | cxc;     // 0..511, tup%8 == cxc (XCD-stable)
    int b    = tup >> 8;
    int rest = tup & 255;
    int head = rest >> 5;
    int o    = rest & 31;

    int tid = threadIdx.x;
    int l, m;
    if (AXIS == 2) { m = tid & 31; l = (tid >> 5) & 7; }
    else           { l = tid & 7;  m = (tid >> 3) & 31; }
    int w0 = slab * 8;

    int spat;
    if (AXIS == 0)      spat = m * 1024 + o * 32 + w0 + l;
    else if (AXIS == 1) spat = o * 1024 + m * 32 + w0 + l;
    else                spat = o * 1024 + (w0 + l) * 32 + m;

    const size_t gbase = ((size_t)b * 576) << 15;
    const float* qp = qkv + gbase + (((size_t)(head * HDIM)) << 15) + spat;
    const float* kp = qp + ((size_t)NC << 15);
    const float* vp = qp + ((size_t)(2 * NC) << 15);

    float Rm[9];
    {
        const float* rp = Rbuf + (((size_t)AXIS * 8 + head) * 32 + m) * 9;
        #pragma unroll
        for (int i = 0; i < 9; ++i) Rm[i] = rp[i];
    }
    const float scale = 0.20412414523193154f;   // 24^-0.5

    // stage + rotate q
    {
        float qv[24];
        #pragma unroll
        for (int d = 0; d < 24; ++d) qv[d] = qp[(size_t)d << 15];
        #pragma unroll
        for (int v = 0; v < 8; ++v) {
            int d0 = v * 3;
            rqL[m][l][d0 + 0] = (Rm[0] * qv[d0] + Rm[1] * qv[d0 + 1] + Rm[2] * qv[d0 + 2]) * scale;
            rqL[m][l][d0 + 1] = (Rm[3] * qv[d0] + Rm[4] * qv[d0 + 1] + Rm[5] * qv[d0 + 2]) * scale;
            rqL[m][l][d0 + 2] = (Rm[6] * qv[d0] + Rm[7] * qv[d0 + 1] + Rm[8] * qv[d0 + 2]) * scale;
        }
    }
    // stage + rotate k
    {
        float kv[24];
        #pragma unroll
        for (int d = 0; d < 24; ++d) kv[d] = kp[(size_t)d << 15];
        #pragma unroll
        for (int v = 0; v < 8; ++v) {
            int d0 = v * 3;
            rkL[m][l][d0 + 0] = Rm[0] * kv[d0] + Rm[1] * kv[d0 + 1] + Rm[2] * kv[d0 + 2];
            rkL[m][l][d0 + 1] = Rm[3] * kv[d0] + Rm[4] * kv[d0 + 1] + Rm[5] * kv[d0 + 2];
            rkL[m][l][d0 + 2] = Rm[6] * kv[d0] + Rm[7] * kv[d0 + 1] + Rm[8] * kv[d0 + 2];
        }
    }
    // stage v (bf16)
    {
        #pragma unroll
        for (int d = 0; d < 24; ++d) vL[m][l][d] = bfr(vp[(size_t)d << 15]);
    }
    __syncthreads();

    // compute: wave wv handles lines 2wv, 2wv+1
    int lane = tid & 63, wvi = tid >> 6;
    int cm = lane & 31, df = lane >> 5;

    #pragma unroll
    for (int li = 0; li < 2; ++li) {
        int lw = wvi * 2 + li;
        float qrow[24];
        #pragma unroll
        for (int i = 0; i < 6; ++i)
            *(float4*)&qrow[i * 4] = *(float4*)&rqL[cm][lw][i * 4];
        float pv[16];
        float mymax = -1e30f;
        #pragma unroll
        for (int j = 0; j < 16; ++j) {
            int mm = df * 16 + j;
            float s = 0.f;
            #pragma unroll
            for (int d = 0; d < 24; d += 4) {
                float4 kk = *(float4*)&rkL[mm][lw][d];
                s += qrow[d] * kk.x + qrow[d + 1] * kk.y + qrow[d + 2] * kk.z + qrow[d + 3] * kk.w;
            }
            pv[j] = s;
            mymax = fmaxf(mymax, s);
        }
        float rmax = fmaxf(mymax, __shfl_xor(mymax, 32));
        float mysum = 0.f;
        #pragma unroll
        for (int j = 0; j < 16; ++j) {
            pv[j] = expf(pv[j] - rmax);
            mysum += pv[j];
        }
        float rsum = mysum + __shfl_xor(mysum, 32);
        float inv = 1.0f / rsum;
        float poth[16];
        #pragma unroll
        for (int j = 0; j < 16; ++j) poth[j] = __shfl_xor(pv[j], 32);

        float o12[12];
        #pragma unroll
        for (int i = 0; i < 12; ++i) o12[i] = 0.f;
        #pragma unroll
        for (int mm = 0; mm < 32; ++mm) {
            int jj = mm & 15;
            float p = (((mm >> 4) == df) ? pv[jj] : poth[jj]) * inv;
            const unsigned* vu = (const unsigned*)&vL[mm][lw][0];
            unsigned u0 = vu[df * 6 + 0], u1 = vu[df * 6 + 1], u2 = vu[df * 6 + 2];
            unsigned u3 = vu[df * 6 + 3], u4 = vu[df * 6 + 4], u5 = vu[df * 6 + 5];
            o12[0]  += p * __uint_as_float(u0 << 16);
            o12[1]  += p * __uint_as_float(u0 & 0xffff0000u);
            o12[2]  += p * __uint_as_float(u1 << 16);
            o12[3]  += p * __uint_as_float(u1 & 0xffff0000u);
            o12[4]  += p * __uint_as_float(u2 << 16);
            o12[5]  += p * __uint_as_float(u2 & 0xffff0000u);
            o12[6]  += p * __uint_as_float(u3 << 16);
            o12[7]  += p * __uint_as_float(u3 & 0xffff0000u);
            o12[8]  += p * __uint_as_float(u4 << 16);
            o12[9]  += p * __uint_as_float(u4 & 0xffff0000u);
            o12[10] += p * __uint_as_float(u5 << 16);
            o12[11] += p * __uint_as_float(u5 & 0xffff0000u);
        }
        // stash into oL (aliases rqL; cells [cm][lw][*] owned by this wave)
        #pragma unroll
        for (int i = 0; i < 12; ++i)
            rqL[cm][lw][df * 12 + i] = o12[i];
    }
    __syncthreads();

    // cooperative coalesced write-out (+= for ACCUM)
    float* ob = outb + (((size_t)(b * NC + head * HDIM)) << 15) + spat;
    #pragma unroll
    for (int d = 0; d < 24; ++d) {
        float val = rqL[m][l][d];
        size_t a = (size_t)d << 15;
        if (ACCUM) ob[a] += val;
        else       ob[a] = val;
    }
}

// ---------------------------------------------------------------------------
extern "C" void kernel_launch(void* const* d_in, const int* in_sizes, int n_in,
                              void* d_out, int out_size, void* d_ws, size_t ws_size,
                              hipStream_t stream)
{
    (void)in_sizes; (void)n_in; (void)out_size; (void)ws_size;
    const float* x      = (const float*)d_in[0];
    const float* pos    = (const float*)d_in[1];
    const float* lp1_w  = (const float*)d_in[2];
    const float* lp1_b  = (const float*)d_in[3];
    const float* lp2_w  = (const float*)d_in[4];
    const float* lp2_b  = (const float*)d_in[5];
    const float* m1_w   = (const float*)d_in[6];
    const float* m1_b   = (const float*)d_in[7];
    const float* m2_w   = (const float*)d_in[8];
    const float* m2_b   = (const float*)d_in[9];
    // d_in[10]=pa_w, d_in[11]=pa_b: per-query softmax bias, cancels -> unused
    const float* qkv_w  = (const float*)d_in[12];
    const float* qkv_b  = (const float*)d_in[13];
    const float* A_d    = (const float*)d_in[14];
    const float* A_h    = (const float*)d_in[15];
    const float* A_w    = (const float*)d_in[16];
    const float* proj_w = (const float*)d_in[17];
    const float* proj_b = (const float*)d_in[18];

    float* ws   = (float*)d_ws;
    float* Rbuf = ws;                       // 8192 floats
    float* buf1 = ws + 8192;                // A: 12,582,912 floats
    float* buf2 = buf1 + 12582912;          // B: 12,582,912 floats
    float* qkvb = buf2 + 12582912;          // C: 37,748,736 floats
    // conv-phase aliases (B region onward, dead later):
    ushort* xb2 = (ushort*)buf2;            // 50.3 MB
    ushort* wb2 = xb2 + 25165824;           //  4.1 MB (spills into C, fine)

    rot_kernel<<<dim3(3), 256, 0, stream>>>(A_d, A_h, A_w, Rbuf);
    xcvt_kernel<<<dim3(512, 2), 256, 0, stream>>>(pos, xb2);
    wcvt_kernel<<<dim3(1008), 256, 0, stream>>>(lp1_w, wb2);
    conv3_mfma<<<dim3(3, 64, 2), 256, 0, stream>>>(xb2, wb2, lp1_b, buf1);

    inorm_gelu_kernel<<<dim3(192, 2), 256, 0, stream>>>(buf1);
    gemm_kernel<0><<<dim3(3, 256, 2), 256, 0, stream>>>(buf1, lp2_w, lp2_b, buf2, nullptr, 192);
    gemm_kernel<0><<<dim3(3, 256, 2), 256, 0, stream>>>(buf2, m1_w, m1_b, buf1, nullptr, 192);
    inorm_gelu_kernel<<<dim3(192, 2), 256, 0, stream>>>(buf1);
    gemm_kernel<1><<<dim3(3, 256, 2), 256, 0, stream>>>(buf1, m2_w, m2_b, buf2, x, 192);
    gemm_kernel<0><<<dim3(9, 256, 2), 256, 0, stream>>>(buf2, qkv_w, qkv_b, qkvb, nullptr, 576);

    // fused attention: axis2 initializes buf1, axes 0/1 accumulate
    attn_fused<2, 0><<<dim3(2048), 256, 0, stream>>>(qkvb, Rbuf, buf1);
    attn_fused<0, 1><<<dim3(2048), 256, 0, stream>>>(qkvb, Rbuf, buf1);
    attn_fused<1, 1><<<dim3(2048), 256, 0, stream>>>(qkvb, Rbuf, buf1);

    gemm_kernel<0><<<dim3(3, 256, 2), 256, 0, stream>>>(buf1, proj_w, proj_b, (float*)d_out, nullptr, 192);
}